// Round 5
// baseline (246.148 us; speedup 1.0000x reference)
//
#include <hip/hip_runtime.h>
#include <hip/hip_bf16.h>

// Shapes: x(8,16,4,64,64) f32, W(256,16,5,5) f32, b(1,1,8,32) f32
// out(8,32,8,64,64) f32.
//
// Verified reinterpretations (R1/R3/R4 passing):
//   conv input  t2[n,a,h,w] = x[b0, fl&15, ci, fl>>10, (fl>>4)&63],
//     fl = a*4096 + h*64 + w, n = ci*8 + b0
//   votes conv-flat (n,oc,y,x) == routing (n, h, w, oa) with
//     h = oc>>2, w = ((oc&3)<<4)|(y>>2), oa = ((y&3)<<6)|x, n = bv*4+civ.
// => routing position (bv,h,w) needs ONE oc, 4 consecutive y, all x, per civ.
// Fused block (bv, yq, q): conv 4civ x 64oc x 4y x 64x -> LDS -> routing -> out.
// Conv core = v_mfma_f32_16x16x32_f16, layouts per m89/m120 (R3/R4-proven).

typedef _Float16 half8 __attribute__((ext_vector_type(8)));
typedef _Float16 half4v __attribute__((ext_vector_type(4)));
typedef float floatx4 __attribute__((ext_vector_type(4)));

#define EPSF 1e-7f

// Prep: blocks [0,256) = pack x->th (R4-proven k_pack2); [256,672) = packw.
__global__ __launch_bounds__(256) void k_prep(const float* __restrict__ x,
                                              const float* __restrict__ W,
                                              _Float16* __restrict__ th,
                                              _Float16* __restrict__ Wp) {
  const int tid = threadIdx.x;
  if (blockIdx.x < 256) {
    __shared__ float lin[32 * 306 + 18];   // [m=32][a1 pad17][w1 pad18]
    const int bid = blockIdx.x;
    const int n   = bid >> 3;
    const int a0h = (bid >> 2) & 1;
    const int W0  = (bid & 3) * 16;
    const int ci = n >> 3, b0 = n & 7;
    const float* xb = x + b0 * 262144 + ci * 4096 + W0;
    for (int p = 0; p < 8; ++p) {
      int rr = p * 64 + (tid >> 2);
      int qq = (tid & 3) * 4;
      int a1 = rr >> 5, m = rr & 31;
      float4 v = *(const float4*)(xb + a1 * 16384 + (a0h * 32 + m) * 64 + qq);
      float* d = lin + m * 306 + a1 * 18 + qq;
      d[0] = v.x; d[1] = v.y; d[2] = v.z; d[3] = v.w;
    }
    __syncthreads();
    _Float16* tb = th + (size_t)n * 65536 + a0h * 32768 + W0 * 128;
    for (int hh = 0; hh < 4; ++hh) {
      int w1 = tid >> 4, a1 = tid & 15;
      half8 v;
#pragma unroll
      for (int j = 0; j < 8; ++j)
        v[j] = (_Float16)lin[(j * 4 + hh) * 306 + a1 * 18 + w1];
      *(half8*)(tb + hh * 8192 + w1 * 128 + a1 * 8) = v;
    }
  } else {
    int id = (blockIdx.x - 256) * 256 + tid;    // 106,496 = 26*4096
    int a  = id & 15;
    int oc = (id >> 4) & 255;
    int kk = id >> 12;
    Wp[id] = (kk < 25) ? (_Float16)W[oc * 400 + a * 25 + kk] : (_Float16)0.0f;
  }
}

// Fused conv + dynamic routing. Block (yq, q, bv), 512 threads (8 waves).
__global__ __launch_bounds__(512, 2) void k_fused(
    const _Float16* __restrict__ th, const _Float16* __restrict__ Wp,
    const float* __restrict__ bias, float* __restrict__ out) {
  __shared__ _Float16 vlds[16384];   // [ocl=64][yl=4][x=64 swizzled]  32 KB
  __shared__ _Float16 slab[8704];    // [a0h=2][row=8][col=68][8a]    17.4 KB
  const int yq = blockIdx.x;   // 0..15
  const int q  = blockIdx.y;   // 0..3
  const int bv = blockIdx.z;   // 0..7
  const int tid  = threadIdx.x;
  const int lane = tid & 63;
  const int wv   = tid >> 6;        // 0..7
  // conv roles (R3-proven fragment mapping):
  const int yl4   = wv >> 1;        // output y row within quad
  const int xh    = wv & 1;         // x half
  const int col16 = lane & 15;
  const int quad  = lane >> 4;
  const int t     = quad >> 1;
  const int a0h   = quad & 1;

  const _Float16* wbase = Wp + (size_t)t * 4096 + (q * 64 + col16) * 16 + a0h * 8;

  half4v vfrag[4][8];               // [civ][pos] routing fragments (64 VGPR)

#pragma unroll
  for (int p = 0; p < 4; ++p) {
    const int n = bv * 4 + p;
    // --- stage slab (rows 4yq-2 .. 4yq+5, zero-padded) ---
    for (int c = tid; c < 1088; c += 512) {
      int ah  = c / 544;
      int rem = c - ah * 544;
      int rr  = rem / 68;
      int cc  = rem - rr * 68;
      int row = yq * 4 + rr - 2;
      int col = cc - 2;
      half8 v = {};
      if (row >= 0 && row < 64 && col >= 0 && col < 64)
        v = *(const half8*)(th + (size_t)(((n * 2 + ah) * 64 + row) * 64 + col) * 8);
      *(half8*)(slab + c * 8) = v;
    }
    __syncthreads();

    // --- conv: wave = 64 oc x (1 y row, 32 x) ---
    floatx4 acc[4][2] = {};
    half8 af[4], an[4], bf2[2];
#pragma unroll
    for (int oct = 0; oct < 4; ++oct)
      af[oct] = *(const half8*)(wbase + oct * 256);

    for (int s = 0; s < 13; ++s) {
      int kkb = 2 * s + t; if (kkb > 24) kkb = 24;   // zero plane 25 on A side
      int ky = kkb / 5, kx = kkb - ky * 5;
      const _Float16* lb = slab + (a0h * 4352 + (yl4 + ky) * 544
                                   + (xh * 32 + col16 + kx) * 8);
      bf2[0] = *(const half8*)(lb);
      bf2[1] = *(const half8*)(lb + 128);
      int sn = (s + 1 < 13) ? s + 1 : s;
#pragma unroll
      for (int oct = 0; oct < 4; ++oct)
        an[oct] = *(const half8*)(wbase + (size_t)sn * 8192 + oct * 256);
#pragma unroll
      for (int oct = 0; oct < 4; ++oct)
#pragma unroll
        for (int xt = 0; xt < 2; ++xt)
          acc[oct][xt] = __builtin_amdgcn_mfma_f32_16x16x32_f16(
              af[oct], bf2[xt], acc[oct][xt], 0, 0, 0);
#pragma unroll
      for (int oct = 0; oct < 4; ++oct) af[oct] = an[oct];
    }

    // --- store votes tile to LDS (x XOR-swizzled by quad: conflict-free) ---
#pragma unroll
    for (int oct = 0; oct < 4; ++oct)
#pragma unroll
      for (int xt = 0; xt < 2; ++xt)
#pragma unroll
        for (int r = 0; r < 4; ++r) {
          int ocl = oct * 16 + quad * 4 + r;
          int xx  = (xh * 32 + xt * 16 + col16) ^ (quad << 4);
          vlds[ocl * 256 + yl4 * 64 + xx] = (_Float16)acc[oct][xt][r];
        }
    __syncthreads();

    // --- routing fragment load: pos ocl = wv*8+k, oa = lane*4..+3 ---
#pragma unroll
    for (int k = 0; k < 8; ++k) {
      int ocl = wv * 8 + k;
      int xr  = ((lane * 4) & 63) ^ (((ocl >> 2) & 3) << 4);
      vfrag[p][k] = *(const half4v*)(vlds + ocl * 256 + (lane >> 4) * 64 + xr);
    }
    __syncthreads();   // protect vlds before next phase overwrites
  }

  // --- dynamic routing (R3/R4-proven math), 8 positions per wave ---
  float4 bia = *(const float4*)(bias + lane * 4);
  const int o  = lane >> 3;
  const int a0 = (lane & 7) * 4;

#pragma unroll
  for (int k = 0; k < 8; ++k) {
    const int ocl = wv * 8 + k;
    const int h = 16 * q + (ocl >> 2);
    const int w = ((ocl & 3) << 4) | yq;

    float4 v[4];
#pragma unroll
    for (int i = 0; i < 4; ++i) {
      half4v hv = vfrag[i][k];
      v[i] = make_float4((float)hv.x, (float)hv.y, (float)hv.z, (float)hv.w);
    }

    float logit[4] = {0.f, 0.f, 0.f, 0.f};
    float act[4];
#pragma unroll
    for (int r = 0; r < 3; ++r) {
      float route[4];
#pragma unroll
      for (int i = 0; i < 4; ++i) {
        float m = logit[i];
        m = fmaxf(m, __shfl_xor(m, 8, 64));
        m = fmaxf(m, __shfl_xor(m, 16, 64));
        m = fmaxf(m, __shfl_xor(m, 32, 64));
        float e = __expf(logit[i] - m);
        float s = e;
        s += __shfl_xor(s, 8, 64);
        s += __shfl_xor(s, 16, 64);
        s += __shfl_xor(s, 32, 64);
        route[i] = e / s;
      }
      float pr[4] = {bia.x, bia.y, bia.z, bia.w};
#pragma unroll
      for (int i = 0; i < 4; ++i) {
        pr[0] = fmaf(route[i], v[i].x, pr[0]);
        pr[1] = fmaf(route[i], v[i].y, pr[1]);
        pr[2] = fmaf(route[i], v[i].z, pr[2]);
        pr[3] = fmaf(route[i], v[i].w, pr[3]);
      }
      float sq = pr[0]*pr[0] + pr[1]*pr[1] + pr[2]*pr[2] + pr[3]*pr[3];
      sq += __shfl_xor(sq, 1, 64);
      sq += __shfl_xor(sq, 2, 64);
      sq += __shfl_xor(sq, 4, 64);
      float scale = sq / (1.f + sq) / sqrtf(sq + EPSF);
#pragma unroll
      for (int j = 0; j < 4; ++j) act[j] = pr[j] * scale;

      if (r < 2) {
#pragma unroll
        for (int i = 0; i < 4; ++i) {
          float ag = v[i].x*act[0] + v[i].y*act[1] + v[i].z*act[2] + v[i].w*act[3];
          ag += __shfl_xor(ag, 1, 64);
          ag += __shfl_xor(ag, 2, 64);
          ag += __shfl_xor(ag, 4, 64);
          logit[i] += ag;
        }
      }
    }

    float* ob = out + (size_t)bv * 1048576 + (size_t)a0 * 32768
                    + o * 4096 + h * 64 + w;
#pragma unroll
    for (int j = 0; j < 4; ++j)
      ob[(size_t)j * 32768] = act[j];
  }
}

extern "C" void kernel_launch(void* const* d_in, const int* in_sizes, int n_in,
                              void* d_out, int out_size, void* d_ws, size_t ws_size,
                              hipStream_t stream) {
  const float* x  = (const float*)d_in[0];
  const float* W  = (const float*)d_in[1];
  const float* b  = (const float*)d_in[2];
  float* out = (float*)d_out;

  _Float16* th = (_Float16*)d_ws;               // 2,097,152 halves (4 MB)
  _Float16* Wp = th + 2097152;                  // 106,496 halves (208 KB)

  k_prep<<<672, 256, 0, stream>>>(x, W, th, Wp);
  k_fused<<<dim3(16, 4, 8), 512, 0, stream>>>(th, Wp, b, out);
}

// Round 6
// 151.357 us; speedup vs baseline: 1.6263x; 1.6263x over previous
//
#include <hip/hip_runtime.h>
#include <hip/hip_bf16.h>

// Shapes: x(8,16,4,64,64) f32, W(256,16,5,5) f32, b(1,1,8,32) f32
// out(8,32,8,64,64) f32.
//
// Verified reinterpretations (R1/R3/R4 passing):
//   conv input  t2[n,a,h,w] = x[b0, fl&15, ci, fl>>10, (fl>>4)&63],
//     fl = a*4096 + h*64 + w, n = ci*8 + b0
//   votes flat (n,oc,y,x) reinterpreted by routing as (bv,civ,h,w,o,ao),
//     n = bv*4 + civ.
// Conv = implicit GEMM on v_mfma_f32_16x16x32_f16 (layouts m89/m120, proven
// R3/R4). R5 lesson: do NOT fuse conv+routing — the fused block's out
// footprint is w-sparse -> 16x write amplification (480 MB measured).

typedef _Float16 half8 __attribute__((ext_vector_type(8)));
typedef _Float16 half4v __attribute__((ext_vector_type(4)));
typedef float floatx4 __attribute__((ext_vector_type(4)));

#define EPSF 1e-7f

// Prep: blocks [0,256) = pack x->th (R4-proven); [256,672) = packw.
__global__ __launch_bounds__(256) void k_prep(const float* __restrict__ x,
                                              const float* __restrict__ W,
                                              _Float16* __restrict__ th,
                                              _Float16* __restrict__ Wp) {
  const int tid = threadIdx.x;
  if (blockIdx.x < 256) {
    __shared__ float lin[32 * 306 + 18];   // [m=32][a1 pad17][w1 pad18]
    const int bid = blockIdx.x;
    const int n   = bid >> 3;
    const int a0h = (bid >> 2) & 1;
    const int W0  = (bid & 3) * 16;
    const int ci = n >> 3, b0 = n & 7;
    const float* xb = x + b0 * 262144 + ci * 4096 + W0;
    for (int p = 0; p < 8; ++p) {
      int rr = p * 64 + (tid >> 2);
      int qq = (tid & 3) * 4;
      int a1 = rr >> 5, m = rr & 31;
      float4 v = *(const float4*)(xb + a1 * 16384 + (a0h * 32 + m) * 64 + qq);
      float* d = lin + m * 306 + a1 * 18 + qq;
      d[0] = v.x; d[1] = v.y; d[2] = v.z; d[3] = v.w;
    }
    __syncthreads();
    _Float16* tb = th + (size_t)n * 65536 + a0h * 32768 + W0 * 128;
    for (int hh = 0; hh < 4; ++hh) {
      int w1 = tid >> 4, a1 = tid & 15;
      half8 v;
#pragma unroll
      for (int j = 0; j < 8; ++j)
        v[j] = (_Float16)lin[(j * 4 + hh) * 306 + a1 * 18 + w1];
      *(half8*)(tb + hh * 8192 + w1 * 128 + a1 * 8) = v;
    }
  } else {
    int id = (blockIdx.x - 256) * 256 + tid;    // 106,496 = 26*4096
    int a  = id & 15;
    int oc = (id >> 4) & 255;
    int kk = id >> 12;
    Wp[id] = (kk < 25) ? (_Float16)W[oc * 400 + a * 25 + kk] : (_Float16)0.0f;
  }
}

// Conv v3: block (n, y2) covers 2 output rows y = 2*y2, 2*y2+1.
// 4 waves; wave wv = oc [wv*64, wv*64+64) x 2y x 64x. 32 MFMA per K-step.
__global__ __launch_bounds__(256) void k_conv(const _Float16* __restrict__ th,
                                              const _Float16* __restrict__ Wp,
                                              _Float16* __restrict__ votes) {
  __shared__ _Float16 slab[6528];     // [a0h=2][rr=6][col=68][8a]  12.75 KB
  const int y2 = blockIdx.x;          // 0..31
  const int n  = blockIdx.y;          // 0..31
  const int y0 = y2 * 2;
  const int tid = threadIdx.x;

  // Stage rows y0-2 .. y0+3 (zero-padded), 816 half8 granules.
  for (int c = tid; c < 816; c += 256) {
    int ah  = c / 408;
    int rem = c - ah * 408;
    int rr  = rem / 68;
    int cc  = rem - rr * 68;
    int row = y0 + rr - 2;
    int col = cc - 2;
    half8 v = {};
    if (row >= 0 && row < 64 && col >= 0 && col < 64)
      v = *(const half8*)(th + (size_t)(((n * 2 + ah) * 64 + row) * 64 + col) * 8);
    *(half8*)(slab + c * 8) = v;
  }
  __syncthreads();

  const int lane  = tid & 63;
  const int wv    = tid >> 6;
  const int col16 = lane & 15;
  const int quad  = lane >> 4;      // 0..3
  const int t     = quad >> 1;      // tap-within-pair
  const int a0h   = quad & 1;       // atom-half
  const int m0    = wv * 64;

  floatx4 acc[2][4][4] = {};        // [yy][oct][xt]

  const _Float16* wbase = Wp + (size_t)t * 4096 + (m0 + col16) * 16 + a0h * 8;
  half8 af[4], an[4];
#pragma unroll
  for (int oct = 0; oct < 4; ++oct)
    af[oct] = *(const half8*)(wbase + oct * 256);

  for (int s = 0; s < 13; ++s) {
    int kkb = 2 * s + t; if (kkb > 24) kkb = 24;   // clamp -> zero plane 25
    int ky = kkb / 5;
    int kx = kkb - ky * 5;
    const _Float16* lb = slab + a0h * 3264 + ky * 544 + (col16 + kx) * 8;
    half8 bf[2][4];
#pragma unroll
    for (int yy = 0; yy < 2; ++yy)
#pragma unroll
      for (int xt = 0; xt < 4; ++xt)
        bf[yy][xt] = *(const half8*)(lb + yy * 544 + xt * 128);
    int sn = (s + 1 < 13) ? s + 1 : s;
#pragma unroll
    for (int oct = 0; oct < 4; ++oct)
      an[oct] = *(const half8*)(wbase + (size_t)sn * 8192 + oct * 256);
#pragma unroll
    for (int oct = 0; oct < 4; ++oct)
#pragma unroll
      for (int yy = 0; yy < 2; ++yy)
#pragma unroll
        for (int xt = 0; xt < 4; ++xt)
          acc[yy][oct][xt] = __builtin_amdgcn_mfma_f32_16x16x32_f16(
              af[oct], bf[yy][xt], acc[yy][oct][xt], 0, 0, 0);
#pragma unroll
    for (int oct = 0; oct < 4; ++oct) af[oct] = an[oct];
  }

  // D[row=quad*4+r][col=col16] -> votes[n, oc, y0+yy, x]
#pragma unroll
  for (int yy = 0; yy < 2; ++yy) {
    _Float16* vbase = votes + (size_t)n * 1048576 + (y0 + yy) * 64;
#pragma unroll
    for (int oct = 0; oct < 4; ++oct)
#pragma unroll
      for (int xt = 0; xt < 4; ++xt)
#pragma unroll
        for (int r = 0; r < 4; ++r) {
          int oc = m0 + oct * 16 + quad * 4 + r;
          int xx = xt * 16 + col16;
          vbase[(size_t)oc * 4096 + xx] = (_Float16)acc[yy][oct][xt][r];
        }
  }
}

// Routing v2 (R4-proven): block = half-row (bv, h, 32 w's); LDS-staged
// coalesced writeout.
__global__ __launch_bounds__(256) void k_routing2(
    const _Float16* __restrict__ votes, const float* __restrict__ bias,
    float* __restrict__ out) {
  __shared__ float so[256 * 36];        // 36 KB
  const int tid  = threadIdx.x;
  const int lane = tid & 63;
  const int wv   = tid >> 6;
  const int bid  = blockIdx.x;          // 1024
  const int bv = bid >> 7;
  const int h  = (bid >> 1) & 63;
  const int W0 = (bid & 1) * 32;

  float4 bia = *(const float4*)(bias + lane * 4);
  const int o  = lane >> 3;
  const int a0 = (lane & 7) * 4;

  for (int k = 0; k < 8; ++k) {
    const int wl = wv * 8 + k;          // 0..31
    const int w  = W0 + wl;
    const _Float16* vb = votes + (size_t)bv * 4194304 + h * 16384 + w * 256 + lane * 4;
    float4 v[4];
#pragma unroll
    for (int i = 0; i < 4; ++i) {
      half4v hv = *(const half4v*)(vb + (size_t)i * 1048576);
      v[i] = make_float4((float)hv.x, (float)hv.y, (float)hv.z, (float)hv.w);
    }

    float logit[4] = {0.f, 0.f, 0.f, 0.f};
    float act[4];

#pragma unroll
    for (int r = 0; r < 3; ++r) {
      float route[4];
#pragma unroll
      for (int i = 0; i < 4; ++i) {
        float m = logit[i];
        m = fmaxf(m, __shfl_xor(m, 8, 64));
        m = fmaxf(m, __shfl_xor(m, 16, 64));
        m = fmaxf(m, __shfl_xor(m, 32, 64));
        float e = __expf(logit[i] - m);
        float s = e;
        s += __shfl_xor(s, 8, 64);
        s += __shfl_xor(s, 16, 64);
        s += __shfl_xor(s, 32, 64);
        route[i] = e / s;
      }
      float pr[4] = {bia.x, bia.y, bia.z, bia.w};
#pragma unroll
      for (int i = 0; i < 4; ++i) {
        pr[0] = fmaf(route[i], v[i].x, pr[0]);
        pr[1] = fmaf(route[i], v[i].y, pr[1]);
        pr[2] = fmaf(route[i], v[i].z, pr[2]);
        pr[3] = fmaf(route[i], v[i].w, pr[3]);
      }
      float sq = pr[0]*pr[0] + pr[1]*pr[1] + pr[2]*pr[2] + pr[3]*pr[3];
      sq += __shfl_xor(sq, 1, 64);
      sq += __shfl_xor(sq, 2, 64);
      sq += __shfl_xor(sq, 4, 64);
      float scale = sq / (1.f + sq) / sqrtf(sq + EPSF);
#pragma unroll
      for (int j = 0; j < 4; ++j) act[j] = pr[j] * scale;

      if (r < 2) {
#pragma unroll
        for (int i = 0; i < 4; ++i) {
          float ag = v[i].x*act[0] + v[i].y*act[1] + v[i].z*act[2] + v[i].w*act[3];
          ag += __shfl_xor(ag, 1, 64);
          ag += __shfl_xor(ag, 2, 64);
          ag += __shfl_xor(ag, 4, 64);
          logit[i] += ag;
        }
      }
    }

#pragma unroll
    for (int j = 0; j < 4; ++j)
      so[((a0 + j) * 8 + o) * 36 + wl] = act[j];
  }
  __syncthreads();

  float* ob = out + (size_t)bv * 1048576 + h * 64 + W0;
  for (int p = 0; p < 8; ++p) {
    int r  = p * 32 + (tid >> 3);
    int w0 = (tid & 7) * 4;
    float4 v = *(const float4*)(so + r * 36 + w0);
    *(float4*)(ob + (size_t)r * 4096 + w0) = v;
  }
}

extern "C" void kernel_launch(void* const* d_in, const int* in_sizes, int n_in,
                              void* d_out, int out_size, void* d_ws, size_t ws_size,
                              hipStream_t stream) {
  const float* x  = (const float*)d_in[0];
  const float* W  = (const float*)d_in[1];
  const float* b  = (const float*)d_in[2];
  float* out = (float*)d_out;

  _Float16* th    = (_Float16*)d_ws;            // 2,097,152 halves (4 MB)
  _Float16* Wp    = th + 2097152;               // 106,496 halves (208 KB)
  _Float16* votes = Wp + 106496;                // 33,554,432 halves (64 MB)

  k_prep<<<672, 256, 0, stream>>>(x, W, th, Wp);
  k_conv<<<dim3(32, 32), 256, 0, stream>>>(th, Wp, votes);
  k_routing2<<<1024, 256, 0, stream>>>(votes, b, out);
}